// Round 13
// baseline (290.259 us; speedup 1.0000x reference)
//
#include <hip/hip_runtime.h>
#include <hip/hip_cooperative_groups.h>
namespace cg = cooperative_groups;

#define B_ 4
#define N_ 325
#define I_ 64
#define H_ 128
#define NODES (B_ * N_)
#define NZMAX 64                    // max nz/row ~35 (5% of 325 + self-loop)
#define NBLK (NODES / 4)            // 325 blocks, 4 nodes each

typedef unsigned short u16;
typedef unsigned int u32;

// f32 weight scratch, written by phase 0 each launch (converts + transposes).
__device__ __align__(16) float g_WT   [192 * 512];   // [k][g]  gates weights
__device__ __align__(16) float g_gcw  [128 * 128];   // [k][o]
__device__ __align__(16) float g_WsT  [128 * 128];   // [k][o]
__device__ __align__(16) float g_WtT  [128 * 128];   // [k][o]
__device__ __align__(16) float g_combT[256 * 128];   // [k][o]
__device__ float g_bias[512];                        // b_ih + b_hh
__device__ float g_svec[896];  // [0]=gc_b [128]=Ws_b [256]=Wt_b [384]=v [512]=ln_g [640]=ln_b [768]=comb_b

// cross-block activation scratch (only tensors read by OTHER blocks)
__device__ __align__(16) float g_support[(size_t)NODES * H_];
__device__ __align__(16) float g_h_graph[(size_t)NODES * H_];
__device__ __align__(16) float g_t_buf  [(size_t)NODES * H_];

__device__ __forceinline__ float bf2f(u16 u) { return __uint_as_float(((u32)u) << 16); }
__device__ __forceinline__ u16 f2bf(float f) {
    u32 u = __float_as_uint(f);
    u += 0x7fffu + ((u >> 16) & 1u);   // RNE
    return (u16)(u >> 16);
}
__device__ __forceinline__ float ldin(const void* p, size_t i, int f32) {
    return f32 ? ((const float*)p)[i] : bf2f(((const u16*)p)[i]);
}
__device__ __forceinline__ void stout(void* p, size_t i, float v, int f32) {
    if (f32) ((float*)p)[i] = v; else ((u16*)p)[i] = f2bf(v);
}
__device__ __forceinline__ float fast_rcp(float x) { return __builtin_amdgcn_rcpf(x); }
__device__ __forceinline__ float sigm(float x) { return fast_rcp(1.f + __expf(-x)); }
__device__ __forceinline__ float tanh_f(float x) {
    x = fminf(15.f, fmaxf(-15.f, x));
    float e = __expf(2.f * x);
    return (e - 1.f) * fast_rcp(e + 1.f);
}
// adj[0,0]==1.0 (self-loop): fp32 low16 = 0x0000, bf16 low16 = 0x3F80.
__device__ __forceinline__ int probe_f32(const void* adj) {
    return ((((const u32*)adj)[0] & 0xFFFFu) != 0x3F80u) ? 1 : 0;
}

struct Params {
    const void *x, *adj, *h, *c;
    const void *W_ih, *W_hh, *b_ih, *b_hh;
    const void *gc_w, *gc_b, *Ws_w, *Ws_b, *Wt_w, *Wt_b;
    const void *vvec, *ln_g, *ln_b, *comb_w, *comb_b;
    void* out;
};

// ---------------------------------------------------------------------------
// Fused cooperative kernel: P0 weight prep | P1 LSTM | P2 graph | P3 attn.
// Block b owns nodes 4b..4b+3 in every phase; per-node state lives in LDS.
// ---------------------------------------------------------------------------
__global__ __launch_bounds__(256, 2) void kfused(Params p)
{
    const int f32 = probe_f32(p.adj);
    const int t = threadIdx.x;
    const int lane = t & 63, w = t >> 6;
    const int node0 = blockIdx.x * 4;
    cg::grid_group grid = cg::this_grid();

    __shared__ __align__(16) float4 xh4[192];    // P1: [k] x {n0..n3}
    __shared__ __align__(16) float4 Gt4[512];    // P1: [g] x {n0..n3}
    __shared__ __align__(16) float4 hl4[128];    // P1->P3: h_lstm [k] x {n}
    __shared__ __align__(16) float4 att4[128];   // P3: h_att  [k] x {n}
    __shared__ __align__(16) float4 hg4[128];    // P2: h_graph [k] x {n}
    __shared__ float s_i[4][H_];                 // P2->P3
    __shared__ float red[4][H_];
    __shared__ float part[2][4][H_];
    __shared__ float nzs[4][NZMAX];
    __shared__ u16 nzi[4][NZMAX];                // P2->P3
    __shared__ float nzv[4][NZMAX];
    __shared__ float mu_[4], rstd_[4], smv[4];
    __shared__ int cnt[4];

    // ---------------- P0: weight prep (grid-stride) ----------------
    {
        const int tid = blockIdx.x * 256 + t;
        const int nth = NBLK * 256;
        const int TOT = 98304 + 16384 * 3 + 32768 + 512 + 896;
        for (int e = tid; e < TOT; e += nth) {
            int i = e;
            if (i < 98304) {                                   // WT[k][g]
                const int k = i >> 9, g = i & 511;
                g_WT[i] = (k < 64) ? ldin(p.W_ih, (size_t)g * 64 + k, f32)
                                   : ldin(p.W_hh, (size_t)g * 128 + (k - 64), f32);
                continue;
            }
            i -= 98304;
            if (i < 16384) { g_gcw[i] = ldin(p.gc_w, i, f32); continue; }
            i -= 16384;
            if (i < 16384) {
                const int k = i >> 7, o = i & 127;
                g_WsT[i] = ldin(p.Ws_w, (size_t)o * 128 + k, f32);
                continue;
            }
            i -= 16384;
            if (i < 16384) {
                const int k = i >> 7, o = i & 127;
                g_WtT[i] = ldin(p.Wt_w, (size_t)o * 128 + k, f32);
                continue;
            }
            i -= 16384;
            if (i < 32768) {
                const int k = i >> 7, o = i & 127;
                g_combT[i] = ldin(p.comb_w, (size_t)o * 256 + k, f32);
                continue;
            }
            i -= 32768;
            if (i < 512) { g_bias[i] = ldin(p.b_ih, i, f32) + ldin(p.b_hh, i, f32); continue; }
            i -= 512;
            {
                const int seg = i >> 7, k = i & 127;
                const void* src = (seg == 0) ? p.gc_b : (seg == 1) ? p.Ws_b : (seg == 2) ? p.Wt_b :
                                  (seg == 3) ? p.vvec : (seg == 4) ? p.ln_g : (seg == 5) ? p.ln_b : p.comb_b;
                g_svec[i] = ldin(src, k, f32);
            }
        }
        // stage activations for P1 while waiting (own nodes, no cross-block dep)
        for (int e = t; e < 768; e += 256) {
            const int n = e / 192, k = e % 192;
            const int node = node0 + n;
            ((float*)&xh4[k])[n] = (k < 192 && k < 64) ? ldin(p.x, (size_t)node * 64 + k, f32)
                                                       : ldin(p.h, (size_t)node * 128 + (k - 64), f32);
        }
    }
    grid.sync();

    // ---------------- P1: gates + cell + support ----------------
    {
        // gates: thread t owns rows g=t and g=t+256
        float a0 = 0.f, a1 = 0.f, a2 = 0.f, a3 = 0.f;
        float b0 = 0.f, b1 = 0.f, b2 = 0.f, b3 = 0.f;
        #pragma unroll 8
        for (int k = 0; k < 192; ++k) {
            const float wv0 = g_WT[(size_t)k * 512 + t];
            const float wv1 = g_WT[(size_t)k * 512 + t + 256];
            const float4 xv = xh4[k];
            a0 = fmaf(xv.x, wv0, a0); a1 = fmaf(xv.y, wv0, a1);
            a2 = fmaf(xv.z, wv0, a2); a3 = fmaf(xv.w, wv0, a3);
            b0 = fmaf(xv.x, wv1, b0); b1 = fmaf(xv.y, wv1, b1);
            b2 = fmaf(xv.z, wv1, b2); b3 = fmaf(xv.w, wv1, b3);
        }
        const float bi0 = g_bias[t], bi1 = g_bias[t + 256];
        Gt4[t]       = make_float4(a0 + bi0, a1 + bi0, a2 + bi0, a3 + bi0);
        Gt4[t + 256] = make_float4(b0 + bi1, b1 + bi1, b2 + bi1, b3 + bi1);
    }
    __syncthreads();
    for (int e = t; e < 512; e += 256) {        // cell nonlinearity
        const int n = e >> 7, hh = e & 127;
        const int node = node0 + n;
        float ig = ((const float*)&Gt4[hh])[n];
        float fg = ((const float*)&Gt4[128 + hh])[n];
        float gv = ((const float*)&Gt4[256 + hh])[n];
        float og = ((const float*)&Gt4[384 + hh])[n];
        float cl = sigm(fg) * ldin(p.c, (size_t)node * 128 + hh, f32) + sigm(ig) * tanh_f(gv);
        float hv = sigm(og) * tanh_f(cl);
        stout(p.out, (size_t)(NODES * H_) + (size_t)node * 128 + hh, cl, f32);
        ((float*)&hl4[hh])[n] = hv;
    }
    __syncthreads();
    {
        // support[n][o] = sum_k hl[n][k] * gc_w[k][o]
        const int o = t & 127;
        #pragma unroll
        for (int ps = 0; ps < 2; ++ps) {
            const int n = (t >> 7) + 2 * ps;    // wave-uniform
            float acc = 0.f;
            #pragma unroll 8
            for (int k = 0; k < 128; ++k)
                acc = fmaf(((const float*)&hl4[k])[n], g_gcw[(size_t)k * 128 + o], acc);
            g_support[(size_t)(node0 + n) * 128 + o] = acc;
        }
        if (t < 4) cnt[t] = 0;
    }
    grid.sync();

    // ---------------- P2: nz compaction + h_graph + s/t proj ----------------
    for (int j = lane; j < N_; j += 64) {       // wave w compacts node node0+w
        float a = ldin(p.adj, (size_t)(node0 + w) * N_ + j, f32);
        if (a != 0.f) {
            int q = atomicAdd(&cnt[w], 1);
            if (q < NZMAX) { nzi[w][q] = (u16)j; nzv[w][q] = a; }
        }
    }
    __syncthreads();
    {
        const int o = t & 127;
        const float gb = g_svec[o];             // gc_b
        #pragma unroll
        for (int ps = 0; ps < 2; ++ps) {
            const int n = (t >> 7) + 2 * ps;
            const int node = node0 + n;
            const int bn = node / N_;
            const int cnn = min(cnt[n], NZMAX);
            float acc = gb;
            for (int q = 0; q < cnn; ++q)
                acc = fmaf(nzv[n][q], g_support[((size_t)bn * N_ + nzi[n][q]) * 128 + o], acc);
            g_h_graph[(size_t)node * 128 + o] = acc;
            ((float*)&hg4[o])[n] = acc;
        }
    }
    __syncthreads();
    {
        // s (t<128, stays in LDS) / t (t>=128, global) projections
        const int o = t & 127;
        const int which = t >> 7;
        const float* WT = which ? g_WtT : g_WsT;
        const float bias = g_svec[128 + which * 128 + o];
        float a0 = 0.f, a1 = 0.f, a2 = 0.f, a3 = 0.f;
        #pragma unroll 8
        for (int k = 0; k < 128; ++k) {
            const float wv = WT[(size_t)k * 128 + o];
            const float4 hv = hg4[k];
            a0 = fmaf(hv.x, wv, a0); a1 = fmaf(hv.y, wv, a1);
            a2 = fmaf(hv.z, wv, a2); a3 = fmaf(hv.w, wv, a3);
        }
        if (which == 0) {
            s_i[0][o] = a0 + bias; s_i[1][o] = a1 + bias;
            s_i[2][o] = a2 + bias; s_i[3][o] = a3 + bias;
        } else {
            g_t_buf[(size_t)(node0 + 0) * 128 + o] = a0 + bias;
            g_t_buf[(size_t)(node0 + 1) * 128 + o] = a1 + bias;
            g_t_buf[(size_t)(node0 + 2) * 128 + o] = a2 + bias;
            g_t_buf[(size_t)(node0 + 3) * 128 + o] = a3 + bias;
        }
    }
    grid.sync();

    // ---------------- P3: scores + softmax + context + LN + combine ----------
    {
        // scores: wave w owns node node0+w; lane covers dims lane, lane+64
        const int bn = (node0 + w) / N_;
        const int cn = min(cnt[w], NZMAX);
        const float v0 = g_svec[384 + lane], v1 = g_svec[384 + 64 + lane];
        const float si0 = s_i[w][lane], si1 = s_i[w][lane + 64];
        for (int q = 0; q < cn; ++q) {
            const float* tj = g_t_buf + ((size_t)bn * N_ + nzi[w][q]) * 128;
            float a = v0 * tanh_f(si0 + tj[lane]) + v1 * tanh_f(si1 + tj[lane + 64]);
            #pragma unroll
            for (int off = 32; off > 0; off >>= 1) a += __shfl_xor(a, off);
            if (lane == 0) nzs[w][q] = a;
        }
    }
    __syncthreads();
    if (t < 4) {                                // softmax (serial, ~17-35 entries)
        const int cn = min(cnt[t], NZMAX);
        float m = -1e30f;
        for (int q = 0; q < cn; ++q) m = fmaxf(m, nzs[t][q]);
        float ssum = 0.f;
        for (int q = 0; q < cn; ++q) { float e = __expf(nzs[t][q] - m); nzs[t][q] = e; ssum += e; }
        smv[t] = fast_rcp(ssum);
    }
    __syncthreads();
    {
        // context (coalesced h_graph rows)
        const int o = t & 127;
        #pragma unroll
        for (int ps = 0; ps < 2; ++ps) {
            const int n = (t >> 7) + 2 * ps;
            const int bn = (node0 + n) / N_;
            const int cn = min(cnt[n], NZMAX);
            float acc = 0.f;
            for (int q = 0; q < cn; ++q)
                acc = fmaf(nzs[n][q], g_h_graph[((size_t)bn * N_ + nzi[n][q]) * 128 + o], acc);
            red[n][o] = acc * smv[n];
        }
    }
    __syncthreads();
    {
        // LayerNorm stats: wave w -> node w
        float x0 = red[w][lane], x1 = red[w][lane + 64];
        float sm = x0 + x1, sq = x0 * x0 + x1 * x1;
        #pragma unroll
        for (int off = 32; off > 0; off >>= 1) {
            sm += __shfl_xor(sm, off);
            sq += __shfl_xor(sq, off);
        }
        if (lane == 0) {
            float mu = sm * (1.f / H_);
            float var = fmaxf(sq * (1.f / H_) - mu * mu, 0.f);
            mu_[w] = mu;
            rstd_[w] = __builtin_amdgcn_rsqf(var + 1e-5f);
        }
    }
    __syncthreads();
    for (int e = t; e < 512; e += 256) {
        const int n = e >> 7, k = e & 127;
        float xn = (red[n][k] - mu_[n]) * rstd_[n];
        ((float*)&att4[k])[n] = g_svec[512 + k] * xn + g_svec[640 + k];
    }
    __syncthreads();
    {
        // combine: coalesced combT, broadcast hl4/att4; k split over halves
        const int o = t & 127, half = t >> 7;
        float a0 = 0.f, a1 = 0.f, a2 = 0.f, a3 = 0.f;
        const float4* src = half ? att4 : hl4;
        const int k0 = half * 128;
        #pragma unroll 8
        for (int kk = 0; kk < 128; ++kk) {
            const float wv = g_combT[(size_t)(k0 + kk) * 128 + o];
            const float4 cv = src[kk];
            a0 = fmaf(cv.x, wv, a0); a1 = fmaf(cv.y, wv, a1);
            a2 = fmaf(cv.z, wv, a2); a3 = fmaf(cv.w, wv, a3);
        }
        part[half][0][o] = a0; part[half][1][o] = a1;
        part[half][2][o] = a2; part[half][3][o] = a3;
    }
    __syncthreads();
    for (int e = t; e < 512; e += 256) {
        const int n = e >> 7, k = e & 127;
        stout(p.out, (size_t)(node0 + n) * 128 + k,
              part[0][n][k] + part[1][n][k] + g_svec[768 + k], f32);
    }
}

// ---------------------------------------------------------------------------
extern "C" void kernel_launch(void* const* d_in, const int* in_sizes, int n_in,
                              void* d_out, int out_size, void* d_ws, size_t ws_size,
                              hipStream_t stream)
{
    (void)in_sizes; (void)n_in; (void)out_size; (void)d_ws; (void)ws_size;
    Params p;
    p.x      = d_in[0];
    p.adj    = d_in[1];
    p.h      = d_in[2];
    p.c      = d_in[3];
    p.W_ih   = d_in[4];
    p.W_hh   = d_in[5];
    p.b_ih   = d_in[6];
    p.b_hh   = d_in[7];
    p.gc_w   = d_in[8];
    p.gc_b   = d_in[9];
    p.Ws_w   = d_in[10];
    p.Ws_b   = d_in[11];
    p.Wt_w   = d_in[12];
    p.Wt_b   = d_in[13];
    p.vvec   = d_in[14];
    p.ln_g   = d_in[15];
    p.ln_b   = d_in[16];
    p.comb_w = d_in[17];
    p.comb_b = d_in[18];
    p.out    = d_out;

    void* args[] = { &p };
    hipLaunchCooperativeKernel(reinterpret_cast<void*>(kfused),
                               dim3(NBLK), dim3(256), args, 0, stream);
}

// Round 14
// 155.677 us; speedup vs baseline: 1.8645x; 1.8645x over previous
//
#include <hip/hip_runtime.h>

#define B_ 4
#define N_ 325
#define I_ 64
#define H_ 128
#define NODES (B_ * N_)
#define NZMAX 64                    // max nz/row ~35 (5% of 325 + self-loop)

typedef unsigned short u16;
typedef unsigned int u32;

// f32 weight scratch, written by k0_prep each launch (converts + transposes).
__device__ __align__(16) float g_WT   [192 * 512];   // [k][g]  gates weights
__device__ __align__(16) float g_gcw  [128 * 128];   // [k][o]
__device__ __align__(16) float g_WsT  [128 * 128];   // [k][o]
__device__ __align__(16) float g_WtT  [128 * 128];   // [k][o]
__device__ __align__(16) float g_combT[256 * 128];   // [k][o]
__device__ float g_bias[512];                        // b_ih + b_hh
__device__ float g_svec[896];  // [0]=gc_b [128]=Ws_b [256]=Wt_b [384]=v [512]=ln_g [640]=ln_b [768]=comb_b

// activation scratch
__device__ __align__(16) float g_support[(size_t)NODES * H_];
__device__ __align__(16) float g_h_graph[(size_t)NODES * H_];
__device__ __align__(16) float g_s_buf  [(size_t)NODES * H_];
__device__ __align__(16) float g_t_buf  [(size_t)NODES * H_];
__device__ __align__(16) float g_hl     [(size_t)NODES * H_];
__device__ u16 g_nz [(size_t)NODES * NZMAX];
__device__ int g_nzc[NODES];

__device__ __forceinline__ float bf2f(u16 u) { return __uint_as_float(((u32)u) << 16); }
__device__ __forceinline__ u16 f2bf(float f) {
    u32 u = __float_as_uint(f);
    u += 0x7fffu + ((u >> 16) & 1u);   // RNE
    return (u16)(u >> 16);
}
__device__ __forceinline__ float ldin(const void* p, size_t i, int f32) {
    return f32 ? ((const float*)p)[i] : bf2f(((const u16*)p)[i]);
}
__device__ __forceinline__ void stout(void* p, size_t i, float v, int f32) {
    if (f32) ((float*)p)[i] = v; else ((u16*)p)[i] = f2bf(v);
}
__device__ __forceinline__ float fast_rcp(float x) { return __builtin_amdgcn_rcpf(x); }
__device__ __forceinline__ float sigm(float x) { return fast_rcp(1.f + __expf(-x)); }
__device__ __forceinline__ float tanh_f(float x) {
    x = fminf(15.f, fmaxf(-15.f, x));
    float e = __expf(2.f * x);
    return (e - 1.f) * fast_rcp(e + 1.f);
}
// adj[0,0]==1.0 (self-loop): fp32 low16 = 0x0000, bf16 low16 = 0x3F80.
__device__ __forceinline__ int probe_f32(const void* adj) {
    return ((((const u32*)adj)[0] & 0xFFFFu) != 0x3F80u) ? 1 : 0;
}

// ---------------------------------------------------------------------------
// K0: weight prep. Blocks 0..39: 64x64 LDS tile transposes (coalesced both
// directions, [64][65] pad = conflict-free). Blocks 40..47: copies + biases.
// ---------------------------------------------------------------------------
__global__ __launch_bounds__(256) void k0_prep(
    const void* __restrict__ W_ih, const void* __restrict__ W_hh,
    const void* __restrict__ b_ih, const void* __restrict__ b_hh,
    const void* __restrict__ gc_w, const void* __restrict__ gc_b,
    const void* __restrict__ Ws_w, const void* __restrict__ Ws_b,
    const void* __restrict__ Wt_w, const void* __restrict__ Wt_b,
    const void* __restrict__ vvec, const void* __restrict__ ln_g,
    const void* __restrict__ ln_b, const void* __restrict__ comb_w,
    const void* __restrict__ comb_b, const void* __restrict__ adj)
{
    const int f32 = probe_f32(adj);
    const int b = blockIdx.x;
    const int t = threadIdx.x;
    if (b < 40) {
        __shared__ float tile[64][65];
        const void* src; float* dst;
        int C, r0, c0, dstStride, dstRowOff;
        if (b < 8)       { src = W_ih;   dst = g_WT;    C = 64;  r0 = b * 64;            c0 = 0;              dstStride = 512; dstRowOff = 0;  }
        else if (b < 24) { int i = b - 8;  src = W_hh;   dst = g_WT;    C = 128; r0 = (i >> 1) * 64; c0 = (i & 1) * 64;  dstStride = 512; dstRowOff = 64; }
        else if (b < 28) { int i = b - 24; src = Ws_w;   dst = g_WsT;   C = 128; r0 = (i >> 1) * 64; c0 = (i & 1) * 64;  dstStride = 128; dstRowOff = 0;  }
        else if (b < 32) { int i = b - 28; src = Wt_w;   dst = g_WtT;   C = 128; r0 = (i >> 1) * 64; c0 = (i & 1) * 64;  dstStride = 128; dstRowOff = 0;  }
        else             { int i = b - 32; src = comb_w; dst = g_combT; C = 256; r0 = (i >> 2) * 64; c0 = (i & 3) * 64;  dstStride = 128; dstRowOff = 0;  }
        const int lane = t & 63, wv = t >> 6;
        for (int rr = wv; rr < 64; rr += 4)
            tile[rr][lane] = ldin(src, (size_t)(r0 + rr) * C + c0 + lane, f32);
        __syncthreads();
        for (int cc = wv; cc < 64; cc += 4)
            dst[(size_t)(dstRowOff + c0 + cc) * dstStride + r0 + lane] = tile[lane][cc];
    } else {
        for (int e = (b - 40) * 256 + t; e < 16384 + 512 + 896; e += 8 * 256) {
            if (e < 16384) { g_gcw[e] = ldin(gc_w, e, f32); }
            else if (e < 16896) {
                const int i = e - 16384;
                g_bias[i] = ldin(b_ih, i, f32) + ldin(b_hh, i, f32);
            } else {
                const int i = e - 16896;
                const int seg = i >> 7, k = i & 127;
                const void* s = (seg == 0) ? gc_b : (seg == 1) ? Ws_b : (seg == 2) ? Wt_b :
                                (seg == 3) ? vvec : (seg == 4) ? ln_g : (seg == 5) ? ln_b : comb_b;
                g_svec[i] = ldin(s, k, f32);
            }
        }
    }
}

// ---------------------------------------------------------------------------
// K1: 650 blocks x 256 threads, 2 nodes/block. Thread t owns gate rows t and
// t+256 (coalesced WT reads, broadcast float2 activations) -> cell -> support.
// ---------------------------------------------------------------------------
__global__ __launch_bounds__(256) void k1_lstm(
    const void* __restrict__ x, const void* __restrict__ h, const void* __restrict__ c,
    const void* __restrict__ adj, void* __restrict__ out)
{
    const int f32 = probe_f32(adj);
    __shared__ __align__(8) float2 xh2[192];     // [k] x {n0,n1}
    __shared__ __align__(8) float2 Gt2[512];     // [g] x {n0,n1}
    __shared__ __align__(8) float2 hl2[128];     // [k] x {n0,n1}
    const int node0 = blockIdx.x * 2;
    const int t = threadIdx.x;

    for (int e = t; e < 384; e += 256) {
        const int n = e / 192, k = e % 192;
        const int node = node0 + n;
        ((float*)&xh2[k])[n] = (k < 64) ? ldin(x, (size_t)node * 64 + k, f32)
                                        : ldin(h, (size_t)node * 128 + (k - 64), f32);
    }
    __syncthreads();

    // gates: rows t and t+256, 2 nodes each
    {
        float a0 = 0.f, a1 = 0.f, b0 = 0.f, b1 = 0.f;
        #pragma unroll 8
        for (int k = 0; k < 192; ++k) {
            const float w0 = g_WT[(size_t)k * 512 + t];
            const float w1 = g_WT[(size_t)k * 512 + t + 256];
            const float2 xv = xh2[k];
            a0 = fmaf(xv.x, w0, a0); a1 = fmaf(xv.y, w0, a1);
            b0 = fmaf(xv.x, w1, b0); b1 = fmaf(xv.y, w1, b1);
        }
        const float bi0 = g_bias[t], bi1 = g_bias[t + 256];
        Gt2[t]       = make_float2(a0 + bi0, a1 + bi0);
        Gt2[t + 256] = make_float2(b0 + bi1, b1 + bi1);
    }
    __syncthreads();

    // cell nonlinearity: t = (n, hh)
    {
        const int n = t >> 7, hh = t & 127;
        const int node = node0 + n;
        const float ig = ((const float*)&Gt2[hh])[n];
        const float fg = ((const float*)&Gt2[128 + hh])[n];
        const float gv = ((const float*)&Gt2[256 + hh])[n];
        const float og = ((const float*)&Gt2[384 + hh])[n];
        const float cl = sigm(fg) * ldin(c, (size_t)node * 128 + hh, f32) + sigm(ig) * tanh_f(gv);
        const float hv = sigm(og) * tanh_f(cl);
        stout(out, (size_t)(NODES * H_) + (size_t)node * 128 + hh, cl, f32);
        g_hl[(size_t)node * 128 + hh] = hv;
        ((float*)&hl2[hh])[n] = hv;
    }
    __syncthreads();

    // support[n][o] = sum_k hl[n][k] * gc_w[k][o]
    {
        const int o = t & 127, n = t >> 7;       // n wave-uniform
        float acc = 0.f;
        #pragma unroll 8
        for (int k = 0; k < 128; ++k)
            acc = fmaf(((const float*)&hl2[k])[n], g_gcw[(size_t)k * 128 + o], acc);
        g_support[(size_t)(node0 + n) * 128 + o] = acc;
    }
}

// ---------------------------------------------------------------------------
// K2: 325 blocks x 256 threads, 4 nodes/block. nz compaction + gather + s/t.
// ---------------------------------------------------------------------------
__global__ __launch_bounds__(256) void k2_graph(const void* __restrict__ adj)
{
    const int f32 = probe_f32(adj);
    __shared__ __align__(16) float4 hg4[128];    // [k] x {n0..n3}
    __shared__ u16 nzi[4][NZMAX];
    __shared__ float nzv[4][NZMAX];
    __shared__ int cnt[4];
    const int node0 = blockIdx.x * 4;
    const int t = threadIdx.x;
    const int lane = t & 63, w = t >> 6;

    if (t < 4) cnt[t] = 0;
    __syncthreads();
    for (int j = lane; j < N_; j += 64) {        // wave w compacts node node0+w
        float a = ldin(adj, (size_t)(node0 + w) * N_ + j, f32);
        if (a != 0.f) {
            int p = atomicAdd(&cnt[w], 1);
            if (p < NZMAX) { nzi[w][p] = (u16)j; nzv[w][p] = a; }
        }
    }
    __syncthreads();
    if (t < 4) g_nzc[node0 + t] = min(cnt[t], NZMAX);
    #pragma unroll
    for (int n = 0; n < 4; ++n) {
        const int cnn = min(cnt[n], NZMAX);
        for (int p = t; p < cnn; p += 256) g_nz[(size_t)(node0 + n) * NZMAX + p] = nzi[n][p];
    }

    // h_graph gather (coalesced support rows)
    const int o = t & 127;
    const float gb = g_svec[o];                  // gc_b
    #pragma unroll
    for (int ps = 0; ps < 2; ++ps) {
        const int n = (t >> 7) + 2 * ps;
        const int node = node0 + n;
        const int bn = node / N_;
        const int cnn = min(cnt[n], NZMAX);
        float acc = gb;
        for (int p = 0; p < cnn; ++p)
            acc = fmaf(nzv[n][p], g_support[((size_t)bn * N_ + nzi[n][p]) * 128 + o], acc);
        g_h_graph[(size_t)node * 128 + o] = acc;
        ((float*)&hg4[o])[n] = acc;
    }
    __syncthreads();

    // s (t<128) / t (t>=128) projections: coalesced W^T, broadcast hg
    {
        const int which = t >> 7;
        const float* WT = which ? g_WtT : g_WsT;
        const float bias = g_svec[128 + which * 128 + o];
        float a0 = 0.f, a1 = 0.f, a2 = 0.f, a3 = 0.f;
        #pragma unroll 8
        for (int k = 0; k < 128; ++k) {
            const float wv = WT[(size_t)k * 128 + o];
            const float4 hv = hg4[k];
            a0 = fmaf(hv.x, wv, a0); a1 = fmaf(hv.y, wv, a1);
            a2 = fmaf(hv.z, wv, a2); a3 = fmaf(hv.w, wv, a3);
        }
        float* dst = which ? g_t_buf : g_s_buf;
        dst[(size_t)(node0 + 0) * 128 + o] = a0 + bias;
        dst[(size_t)(node0 + 1) * 128 + o] = a1 + bias;
        dst[(size_t)(node0 + 2) * 128 + o] = a2 + bias;
        dst[(size_t)(node0 + 3) * 128 + o] = a3 + bias;
    }
}

// ---------------------------------------------------------------------------
// K3: 325 blocks x 256 threads, 4 nodes/block. scores+softmax+ctx+LN+combine.
// ---------------------------------------------------------------------------
__global__ __launch_bounds__(256) void k3_attn(
    const void* __restrict__ adj, void* __restrict__ out)
{
    const int f32 = probe_f32(adj);
    __shared__ __align__(16) float4 comb4[256];  // [k] x {n0..n3}: [h_lstm | h_att]
    __shared__ float s_i[4][H_];
    __shared__ float red[4][H_];
    __shared__ float nzs[4][NZMAX];
    __shared__ u16 nzi[4][NZMAX];
    __shared__ float part[2][4][H_];
    __shared__ float mu_[4], rstd_[4], smv[4];
    __shared__ int cnt[4];
    const int node0 = blockIdx.x * 4;
    const int t = threadIdx.x;
    const int lane = t & 63, w = t >> 6;

    if (t < 4) cnt[t] = g_nzc[node0 + t];
    for (int e = t; e < 512; e += 256) {
        const int n = e >> 7, k = e & 127;
        const int node = node0 + n;
        s_i[n][k] = g_s_buf[(size_t)node * 128 + k];
        ((float*)&comb4[k])[n] = g_hl[(size_t)node * 128 + k];
    }
    __syncthreads();
    #pragma unroll
    for (int n = 0; n < 4; ++n)
        for (int p = t; p < cnt[n]; p += 256) nzi[n][p] = g_nz[(size_t)(node0 + n) * NZMAX + p];
    __syncthreads();

    // scores: wave w owns node node0+w; lane covers dims lane, lane+64
    {
        const int bn = (node0 + w) / N_;
        const int cn = cnt[w];
        const float v0 = g_svec[384 + lane], v1 = g_svec[384 + 64 + lane];
        const float si0 = s_i[w][lane], si1 = s_i[w][lane + 64];
        for (int p = 0; p < cn; ++p) {
            const float* tj = g_t_buf + ((size_t)bn * N_ + nzi[w][p]) * 128;
            float a = v0 * tanh_f(si0 + tj[lane]) + v1 * tanh_f(si1 + tj[lane + 64]);
            #pragma unroll
            for (int off = 32; off > 0; off >>= 1) a += __shfl_xor(a, off);
            if (lane == 0) nzs[w][p] = a;
        }
    }
    __syncthreads();

    if (t < 4) {                                 // softmax (serial, ~17-35)
        const int cn = cnt[t];
        float m = -1e30f;
        for (int p = 0; p < cn; ++p) m = fmaxf(m, nzs[t][p]);
        float ssum = 0.f;
        for (int p = 0; p < cn; ++p) { float e = __expf(nzs[t][p] - m); nzs[t][p] = e; ssum += e; }
        smv[t] = fast_rcp(ssum);
    }
    __syncthreads();

    // context (coalesced h_graph rows)
    const int o = t & 127;
    #pragma unroll
    for (int ps = 0; ps < 2; ++ps) {
        const int n = (t >> 7) + 2 * ps;
        const int bn = (node0 + n) / N_;
        const int cn = cnt[n];
        float acc = 0.f;
        for (int p = 0; p < cn; ++p)
            acc = fmaf(nzs[n][p], g_h_graph[((size_t)bn * N_ + nzi[n][p]) * 128 + o], acc);
        red[n][o] = acc * smv[n];
    }
    __syncthreads();

    // LayerNorm stats: wave w -> node w
    {
        float x0 = red[w][lane], x1 = red[w][lane + 64];
        float sm = x0 + x1, sq = x0 * x0 + x1 * x1;
        #pragma unroll
        for (int off = 32; off > 0; off >>= 1) {
            sm += __shfl_xor(sm, off);
            sq += __shfl_xor(sq, off);
        }
        if (lane == 0) {
            float mu = sm * (1.f / H_);
            float var = fmaxf(sq * (1.f / H_) - mu * mu, 0.f);
            mu_[w] = mu;
            rstd_[w] = __builtin_amdgcn_rsqf(var + 1e-5f);
        }
    }
    __syncthreads();
    for (int e = t; e < 512; e += 256) {
        const int n = e >> 7, k = e & 127;
        float xn = (red[n][k] - mu_[n]) * rstd_[n];
        ((float*)&comb4[128 + k])[n] = g_svec[512 + k] * xn + g_svec[640 + k];
    }
    __syncthreads();

    // combine: coalesced combT, broadcast comb4; k split over halves
    {
        const int half = t >> 7;
        float a0 = 0.f, a1 = 0.f, a2 = 0.f, a3 = 0.f;
        const int k0 = half * 128;
        #pragma unroll 8
        for (int kk = 0; kk < 128; ++kk) {
            const float wv = g_combT[(size_t)(k0 + kk) * 128 + o];
            const float4 cv = comb4[k0 + kk];
            a0 = fmaf(cv.x, wv, a0); a1 = fmaf(cv.y, wv, a1);
            a2 = fmaf(cv.z, wv, a2); a3 = fmaf(cv.w, wv, a3);
        }
        part[half][0][o] = a0; part[half][1][o] = a1;
        part[half][2][o] = a2; part[half][3][o] = a3;
    }
    __syncthreads();
    for (int e = t; e < 512; e += 256) {
        const int n = e >> 7, k = e & 127;
        stout(out, (size_t)(node0 + n) * 128 + k,
              part[0][n][k] + part[1][n][k] + g_svec[768 + k], f32);
    }
}

// ---------------------------------------------------------------------------
extern "C" void kernel_launch(void* const* d_in, const int* in_sizes, int n_in,
                              void* d_out, int out_size, void* d_ws, size_t ws_size,
                              hipStream_t stream)
{
    (void)in_sizes; (void)n_in; (void)out_size; (void)d_ws; (void)ws_size;
    const void* x      = d_in[0];
    const void* adj    = d_in[1];
    const void* h      = d_in[2];
    const void* c      = d_in[3];
    const void* W_ih   = d_in[4];
    const void* W_hh   = d_in[5];
    const void* b_ih   = d_in[6];
    const void* b_hh   = d_in[7];
    const void* gc_w   = d_in[8];
    const void* gc_b   = d_in[9];
    const void* Ws_w   = d_in[10];
    const void* Ws_b   = d_in[11];
    const void* Wt_w   = d_in[12];
    const void* Wt_b   = d_in[13];
    const void* vvec   = d_in[14];
    const void* ln_g   = d_in[15];
    const void* ln_b   = d_in[16];
    const void* comb_w = d_in[17];
    const void* comb_b = d_in[18];

    k0_prep <<<48, 256, 0, stream>>>(W_ih, W_hh, b_ih, b_hh, gc_w, gc_b,
                                     Ws_w, Ws_b, Wt_w, Wt_b, vvec, ln_g, ln_b,
                                     comb_w, comb_b, adj);
    k1_lstm <<<NODES / 2, 256, 0, stream>>>(x, h, c, adj, d_out);
    k2_graph<<<NODES / 4, 256, 0, stream>>>(adj);
    k3_attn <<<NODES / 4, 256, 0, stream>>>(adj, d_out);
}

// Round 15
// 151.598 us; speedup vs baseline: 1.9147x; 1.0269x over previous
//
#include <hip/hip_runtime.h>

#define B_ 4
#define N_ 325
#define I_ 64
#define H_ 128
#define NODES (B_ * N_)
#define NZMAX 64                    // max nz/row ~35 (5% of 325 + self-loop)

typedef unsigned short u16;
typedef unsigned int u32;

// f32 weight scratch, written by k0_prep each launch (converts + transposes).
__device__ __align__(16) float g_WT   [192 * 512];   // [k][g]  gates weights
__device__ __align__(16) float g_gcw  [128 * 128];   // [k][o]
__device__ __align__(16) float g_WsT  [128 * 128];   // [k][o]
__device__ __align__(16) float g_WtT  [128 * 128];   // [k][o]
__device__ __align__(16) float g_combT[256 * 128];   // [k][o]
__device__ float g_bias[512];                        // b_ih + b_hh
__device__ float g_svec[896];  // [0]=gc_b [128]=Ws_b [256]=Wt_b [384]=v [512]=ln_g [640]=ln_b [768]=comb_b

// activation scratch
__device__ __align__(16) float g_support[(size_t)NODES * H_];
__device__ __align__(16) float g_h_graph[(size_t)NODES * H_];
__device__ __align__(16) float g_s_buf  [(size_t)NODES * H_];
__device__ __align__(16) float g_t_buf  [(size_t)NODES * H_];
__device__ __align__(16) float g_hl     [(size_t)NODES * H_];
__device__ u16 g_nz [(size_t)NODES * NZMAX];
__device__ int g_nzc[NODES];

__device__ __forceinline__ float bf2f(u16 u) { return __uint_as_float(((u32)u) << 16); }
__device__ __forceinline__ u16 f2bf(float f) {
    u32 u = __float_as_uint(f);
    u += 0x7fffu + ((u >> 16) & 1u);   // RNE
    return (u16)(u >> 16);
}
__device__ __forceinline__ float ldin(const void* p, size_t i, int f32) {
    return f32 ? ((const float*)p)[i] : bf2f(((const u16*)p)[i]);
}
__device__ __forceinline__ void stout(void* p, size_t i, float v, int f32) {
    if (f32) ((float*)p)[i] = v; else ((u16*)p)[i] = f2bf(v);
}
__device__ __forceinline__ float fast_rcp(float x) { return __builtin_amdgcn_rcpf(x); }
__device__ __forceinline__ float sigm(float x) { return fast_rcp(1.f + __expf(-x)); }
__device__ __forceinline__ float tanh_f(float x) {
    x = fminf(15.f, fmaxf(-15.f, x));
    float e = __expf(2.f * x);
    return (e - 1.f) * fast_rcp(e + 1.f);
}
// adj[0,0]==1.0 (self-loop): fp32 low16 = 0x0000, bf16 low16 = 0x3F80.
__device__ __forceinline__ int probe_f32(const void* adj) {
    return ((((const u32*)adj)[0] & 0xFFFFu) != 0x3F80u) ? 1 : 0;
}

// ---------------------------------------------------------------------------
// K0: weight prep. Blocks 0..39: 64x64 LDS tile transposes (coalesced both
// directions, [64][65] pad = conflict-free). Blocks 40..47: copies + biases.
// ---------------------------------------------------------------------------
__global__ __launch_bounds__(256) void k0_prep(
    const void* __restrict__ W_ih, const void* __restrict__ W_hh,
    const void* __restrict__ b_ih, const void* __restrict__ b_hh,
    const void* __restrict__ gc_w, const void* __restrict__ gc_b,
    const void* __restrict__ Ws_w, const void* __restrict__ Ws_b,
    const void* __restrict__ Wt_w, const void* __restrict__ Wt_b,
    const void* __restrict__ vvec, const void* __restrict__ ln_g,
    const void* __restrict__ ln_b, const void* __restrict__ comb_w,
    const void* __restrict__ comb_b, const void* __restrict__ adj)
{
    const int f32 = probe_f32(adj);
    const int b = blockIdx.x;
    const int t = threadIdx.x;
    if (b < 40) {
        __shared__ float tile[64][65];
        const void* src; float* dst;
        int C, r0, c0, dstStride, dstRowOff;
        if (b < 8)       { src = W_ih;   dst = g_WT;    C = 64;  r0 = b * 64;            c0 = 0;              dstStride = 512; dstRowOff = 0;  }
        else if (b < 24) { int i = b - 8;  src = W_hh;   dst = g_WT;    C = 128; r0 = (i >> 1) * 64; c0 = (i & 1) * 64;  dstStride = 512; dstRowOff = 64; }
        else if (b < 28) { int i = b - 24; src = Ws_w;   dst = g_WsT;   C = 128; r0 = (i >> 1) * 64; c0 = (i & 1) * 64;  dstStride = 128; dstRowOff = 0;  }
        else if (b < 32) { int i = b - 28; src = Wt_w;   dst = g_WtT;   C = 128; r0 = (i >> 1) * 64; c0 = (i & 1) * 64;  dstStride = 128; dstRowOff = 0;  }
        else             { int i = b - 32; src = comb_w; dst = g_combT; C = 256; r0 = (i >> 2) * 64; c0 = (i & 3) * 64;  dstStride = 128; dstRowOff = 0;  }
        const int lane = t & 63, wv = t >> 6;
        for (int rr = wv; rr < 64; rr += 4)
            tile[rr][lane] = ldin(src, (size_t)(r0 + rr) * C + c0 + lane, f32);
        __syncthreads();
        for (int cc = wv; cc < 64; cc += 4)
            dst[(size_t)(dstRowOff + c0 + cc) * dstStride + r0 + lane] = tile[lane][cc];
    } else {
        for (int e = (b - 40) * 256 + t; e < 16384 + 512 + 896; e += 8 * 256) {
            if (e < 16384) { g_gcw[e] = ldin(gc_w, e, f32); }
            else if (e < 16896) {
                const int i = e - 16384;
                g_bias[i] = ldin(b_ih, i, f32) + ldin(b_hh, i, f32);
            } else {
                const int i = e - 16896;
                const int seg = i >> 7, k = i & 127;
                const void* s = (seg == 0) ? gc_b : (seg == 1) ? Ws_b : (seg == 2) ? Wt_b :
                                (seg == 3) ? vvec : (seg == 4) ? ln_g : (seg == 5) ? ln_b : comb_b;
                g_svec[i] = ldin(s, k, f32);
            }
        }
    }
}

// ---------------------------------------------------------------------------
// K1: 325 blocks x 512 threads, 4 nodes/block (R12 geometry: minimal L2
// weight re-reads). Thread t owns gate row t; coalesced WT, broadcast float4.
// ---------------------------------------------------------------------------
__global__ __launch_bounds__(512) void k1_lstm(
    const void* __restrict__ x, const void* __restrict__ h, const void* __restrict__ c,
    const void* __restrict__ adj, void* __restrict__ out)
{
    const int f32 = probe_f32(adj);
    __shared__ __align__(16) float4 xh4[192];    // [k] x {n0..n3}
    __shared__ __align__(16) float4 Gt4[512];    // [g] x {n0..n3}
    __shared__ __align__(16) float4 hl4[128];    // [k] x {n0..n3}
    const int node0 = blockIdx.x * 4;
    const int t = threadIdx.x;

    for (int e = t; e < 768; e += 512) {
        const int n = e / 192, k = e % 192;
        const int node = node0 + n;
        ((float*)&xh4[k])[n] = (k < 64) ? ldin(x, (size_t)node * 64 + k, f32)
                                        : ldin(h, (size_t)node * 128 + (k - 64), f32);
    }
    __syncthreads();

    // gates: g = t; 192 coalesced weight loads, broadcast activations
    {
        const int g = t;
        float a0 = 0.f, a1 = 0.f, a2 = 0.f, a3 = 0.f;
        #pragma unroll 8
        for (int k = 0; k < 192; ++k) {
            const float wv = g_WT[(size_t)k * 512 + g];
            const float4 xv = xh4[k];
            a0 = fmaf(xv.x, wv, a0); a1 = fmaf(xv.y, wv, a1);
            a2 = fmaf(xv.z, wv, a2); a3 = fmaf(xv.w, wv, a3);
        }
        const float bias = g_bias[g];
        Gt4[g] = make_float4(a0 + bias, a1 + bias, a2 + bias, a3 + bias);
    }
    __syncthreads();

    // cell nonlinearity: t = (n, hh)
    {
        const int n = t >> 7, hh = t & 127;
        const int node = node0 + n;
        const float ig = ((const float*)&Gt4[hh])[n];
        const float fg = ((const float*)&Gt4[128 + hh])[n];
        const float gv = ((const float*)&Gt4[256 + hh])[n];
        const float og = ((const float*)&Gt4[384 + hh])[n];
        const float cl = sigm(fg) * ldin(c, (size_t)node * 128 + hh, f32) + sigm(ig) * tanh_f(gv);
        const float hv = sigm(og) * tanh_f(cl);
        stout(out, (size_t)(NODES * H_) + (size_t)node * 128 + hh, cl, f32);
        g_hl[(size_t)node * 128 + hh] = hv;
        ((float*)&hl4[hh])[n] = hv;
    }
    __syncthreads();

    // support[n][o] = sum_k hl[n][k] * gc_w[k][o]; coalesced gcw, broadcast hl
    {
        const int o = t & 127, n = t >> 7;       // n wave-uniform
        float acc = 0.f;
        #pragma unroll 8
        for (int k = 0; k < 128; ++k)
            acc = fmaf(((const float*)&hl4[k])[n], g_gcw[(size_t)k * 128 + o], acc);
        g_support[(size_t)(node0 + n) * 128 + o] = acc;
    }
}

// ---------------------------------------------------------------------------
// K2: 325 blocks x 256 threads, 4 nodes/block. nz compaction + gather + s/t.
// ---------------------------------------------------------------------------
__global__ __launch_bounds__(256) void k2_graph(const void* __restrict__ adj)
{
    const int f32 = probe_f32(adj);
    __shared__ __align__(16) float4 hg4[128];    // [k] x {n0..n3}
    __shared__ u16 nzi[4][NZMAX];
    __shared__ float nzv[4][NZMAX];
    __shared__ int cnt[4];
    const int node0 = blockIdx.x * 4;
    const int t = threadIdx.x;
    const int lane = t & 63, w = t >> 6;

    if (t < 4) cnt[t] = 0;
    __syncthreads();
    for (int j = lane; j < N_; j += 64) {        // wave w compacts node node0+w
        float a = ldin(adj, (size_t)(node0 + w) * N_ + j, f32);
        if (a != 0.f) {
            int p = atomicAdd(&cnt[w], 1);
            if (p < NZMAX) { nzi[w][p] = (u16)j; nzv[w][p] = a; }
        }
    }
    __syncthreads();
    if (t < 4) g_nzc[node0 + t] = min(cnt[t], NZMAX);
    #pragma unroll
    for (int n = 0; n < 4; ++n) {
        const int cnn = min(cnt[n], NZMAX);
        for (int p = t; p < cnn; p += 256) g_nz[(size_t)(node0 + n) * NZMAX + p] = nzi[n][p];
    }

    // h_graph gather: dual accumulators (even/odd p) for 2x MLP
    const int o = t & 127;
    const float gb = g_svec[o];                  // gc_b
    #pragma unroll
    for (int ps = 0; ps < 2; ++ps) {
        const int n = (t >> 7) + 2 * ps;
        const int node = node0 + n;
        const int bn = node / N_;
        const int cnn = min(cnt[n], NZMAX);
        float accA = 0.f, accB = 0.f;
        int p = 0;
        for (; p + 1 < cnn; p += 2) {
            accA = fmaf(nzv[n][p],     g_support[((size_t)bn * N_ + nzi[n][p])     * 128 + o], accA);
            accB = fmaf(nzv[n][p + 1], g_support[((size_t)bn * N_ + nzi[n][p + 1]) * 128 + o], accB);
        }
        if (p < cnn)
            accA = fmaf(nzv[n][p], g_support[((size_t)bn * N_ + nzi[n][p]) * 128 + o], accA);
        const float acc = accA + accB + gb;
        g_h_graph[(size_t)node * 128 + o] = acc;
        ((float*)&hg4[o])[n] = acc;
    }
    __syncthreads();

    // s (t<128) / t (t>=128) projections: coalesced W^T, broadcast hg
    {
        const int which = t >> 7;
        const float* WT = which ? g_WtT : g_WsT;
        const float bias = g_svec[128 + which * 128 + o];
        float a0 = 0.f, a1 = 0.f, a2 = 0.f, a3 = 0.f;
        #pragma unroll 8
        for (int k = 0; k < 128; ++k) {
            const float wv = WT[(size_t)k * 128 + o];
            const float4 hv = hg4[k];
            a0 = fmaf(hv.x, wv, a0); a1 = fmaf(hv.y, wv, a1);
            a2 = fmaf(hv.z, wv, a2); a3 = fmaf(hv.w, wv, a3);
        }
        float* dst = which ? g_t_buf : g_s_buf;
        dst[(size_t)(node0 + 0) * 128 + o] = a0 + bias;
        dst[(size_t)(node0 + 1) * 128 + o] = a1 + bias;
        dst[(size_t)(node0 + 2) * 128 + o] = a2 + bias;
        dst[(size_t)(node0 + 3) * 128 + o] = a3 + bias;
    }
}

// ---------------------------------------------------------------------------
// K3: 325 blocks x 256 threads, 4 nodes/block. scores+softmax+ctx+LN+combine.
// ---------------------------------------------------------------------------
__global__ __launch_bounds__(256) void k3_attn(
    const void* __restrict__ adj, void* __restrict__ out)
{
    const int f32 = probe_f32(adj);
    __shared__ __align__(16) float4 comb4[256];  // [k] x {n0..n3}: [h_lstm | h_att]
    __shared__ float s_i[4][H_];
    __shared__ float red[4][H_];
    __shared__ float nzs[4][NZMAX];
    __shared__ u16 nzi[4][NZMAX];
    __shared__ float part[2][4][H_];
    __shared__ float mu_[4], rstd_[4], smv[4];
    __shared__ int cnt[4];
    const int node0 = blockIdx.x * 4;
    const int t = threadIdx.x;
    const int lane = t & 63, w = t >> 6;

    if (t < 4) cnt[t] = g_nzc[node0 + t];
    for (int e = t; e < 512; e += 256) {
        const int n = e >> 7, k = e & 127;
        const int node = node0 + n;
        s_i[n][k] = g_s_buf[(size_t)node * 128 + k];
        ((float*)&comb4[k])[n] = g_hl[(size_t)node * 128 + k];
    }
    __syncthreads();
    #pragma unroll
    for (int n = 0; n < 4; ++n)
        for (int p = t; p < cnt[n]; p += 256) nzi[n][p] = g_nz[(size_t)(node0 + n) * NZMAX + p];
    __syncthreads();

    // scores: wave w owns node node0+w; half-wave per neighbor (2 p / iter),
    // sub-lane sl covers dims sl, sl+32, sl+64, sl+96; 5-step 32-lane reduce.
    {
        const int bn = (node0 + w) / N_;
        const int cn = cnt[w];
        const int sl = lane & 31, hf = lane >> 5;
        const float v0 = g_svec[384 + sl],      v1 = g_svec[384 + 32 + sl];
        const float v2 = g_svec[384 + 64 + sl], v3 = g_svec[384 + 96 + sl];
        const float s0 = s_i[w][sl],      s1 = s_i[w][sl + 32];
        const float s2 = s_i[w][sl + 64], s3 = s_i[w][sl + 96];
        for (int base = 0; base < cn; base += 2) {
            const int p = base + hf;
            float a = 0.f;
            if (p < cn) {
                const float* tj = g_t_buf + ((size_t)bn * N_ + nzi[w][p]) * 128;
                a = v0 * tanh_f(s0 + tj[sl])      + v1 * tanh_f(s1 + tj[sl + 32])
                  + v2 * tanh_f(s2 + tj[sl + 64]) + v3 * tanh_f(s3 + tj[sl + 96]);
            }
            a += __shfl_xor(a, 16); a += __shfl_xor(a, 8);
            a += __shfl_xor(a, 4);  a += __shfl_xor(a, 2); a += __shfl_xor(a, 1);
            if (sl == 0 && p < cn) nzs[w][p] = a;
        }
    }
    __syncthreads();

    if (t < 4) {                                 // softmax (serial, ~17-35)
        const int cn = cnt[t];
        float m = -1e30f;
        for (int p = 0; p < cn; ++p) m = fmaxf(m, nzs[t][p]);
        float ssum = 0.f;
        for (int p = 0; p < cn; ++p) { float e = __expf(nzs[t][p] - m); nzs[t][p] = e; ssum += e; }
        smv[t] = fast_rcp(ssum);
    }
    __syncthreads();

    // context: dual accumulators (even/odd p)
    const int o = t & 127;
    #pragma unroll
    for (int ps = 0; ps < 2; ++ps) {
        const int n = (t >> 7) + 2 * ps;
        const int bn = (node0 + n) / N_;
        const int cn = cnt[n];
        float accA = 0.f, accB = 0.f;
        int p = 0;
        for (; p + 1 < cn; p += 2) {
            accA = fmaf(nzs[n][p],     g_h_graph[((size_t)bn * N_ + nzi[n][p])     * 128 + o], accA);
            accB = fmaf(nzs[n][p + 1], g_h_graph[((size_t)bn * N_ + nzi[n][p + 1]) * 128 + o], accB);
        }
        if (p < cn)
            accA = fmaf(nzs[n][p], g_h_graph[((size_t)bn * N_ + nzi[n][p]) * 128 + o], accA);
        red[n][o] = (accA + accB) * smv[n];
    }
    __syncthreads();

    // LayerNorm stats: wave w -> node w
    {
        float x0 = red[w][lane], x1 = red[w][lane + 64];
        float sm = x0 + x1, sq = x0 * x0 + x1 * x1;
        #pragma unroll
        for (int off = 32; off > 0; off >>= 1) {
            sm += __shfl_xor(sm, off);
            sq += __shfl_xor(sq, off);
        }
        if (lane == 0) {
            float mu = sm * (1.f / H_);
            float var = fmaxf(sq * (1.f / H_) - mu * mu, 0.f);
            mu_[w] = mu;
            rstd_[w] = __builtin_amdgcn_rsqf(var + 1e-5f);
        }
    }
    __syncthreads();
    for (int e = t; e < 512; e += 256) {
        const int n = e >> 7, k = e & 127;
        float xn = (red[n][k] - mu_[n]) * rstd_[n];
        ((float*)&comb4[128 + k])[n] = g_svec[512 + k] * xn + g_svec[640 + k];
    }
    __syncthreads();

    // combine: coalesced combT, broadcast comb4; k split over halves
    {
        const int half = t >> 7;
        float a0 = 0.f, a1 = 0.f, a2 = 0.f, a3 = 0.f;
        const int k0 = half * 128;
        #pragma unroll 8
        for (int kk = 0; kk < 128; ++kk) {
            const float wv = g_combT[(size_t)(k0 + kk) * 128 + o];
            const float4 cv = comb4[k0 + kk];
            a0 = fmaf(cv.x, wv, a0); a1 = fmaf(cv.y, wv, a1);
            a2 = fmaf(cv.z, wv, a2); a3 = fmaf(cv.w, wv, a3);
        }
        part[half][0][o] = a0; part[half][1][o] = a1;
        part[half][2][o] = a2; part[half][3][o] = a3;
    }
    __syncthreads();
    for (int e = t; e < 512; e += 256) {
        const int n = e >> 7, k = e & 127;
        stout(out, (size_t)(node0 + n) * 128 + k,
              part[0][n][k] + part[1][n][k] + g_svec[768 + k], f32);
    }
}

// ---------------------------------------------------------------------------
extern "C" void kernel_launch(void* const* d_in, const int* in_sizes, int n_in,
                              void* d_out, int out_size, void* d_ws, size_t ws_size,
                              hipStream_t stream)
{
    (void)in_sizes; (void)n_in; (void)out_size; (void)d_ws; (void)ws_size;
    const void* x      = d_in[0];
    const void* adj    = d_in[1];
    const void* h      = d_in[2];
    const void* c      = d_in[3];
    const void* W_ih   = d_in[4];
    const void* W_hh   = d_in[5];
    const void* b_ih   = d_in[6];
    const void* b_hh   = d_in[7];
    const void* gc_w   = d_in[8];
    const void* gc_b   = d_in[9];
    const void* Ws_w   = d_in[10];
    const void* Ws_b   = d_in[11];
    const void* Wt_w   = d_in[12];
    const void* Wt_b   = d_in[13];
    const void* vvec   = d_in[14];
    const void* ln_g   = d_in[15];
    const void* ln_b   = d_in[16];
    const void* comb_w = d_in[17];
    const void* comb_b = d_in[18];

    k0_prep <<<48, 256, 0, stream>>>(W_ih, W_hh, b_ih, b_hh, gc_w, gc_b,
                                     Ws_w, Ws_b, Wt_w, Wt_b, vvec, ln_g, ln_b,
                                     comb_w, comb_b, adj);
    k1_lstm <<<NODES / 4, 512, 0, stream>>>(x, h, c, adj, d_out);
    k2_graph<<<NODES / 4, 256, 0, stream>>>(adj);
    k3_attn <<<NODES / 4, 256, 0, stream>>>(adj, d_out);
}